// Round 5
// baseline (1045.635 us; speedup 1.0000x reference)
//
#include <hip/hip_runtime.h>
#include <hip/hip_fp16.h>

#define N_NODES 30000
#define N_EDGES 240000
#define EMB     300
#define NPAD    30080   // 235 * 128
#define K1      320     // padded EMB (gemm1 K, agg cols, fp16)
#define NP1     640     // padded 2*EMB (gemm1 out cols = gemm2 K)
#define NP2     384     // gemm2 padded col count / h2 fp16 row stride
#define HSH     304     // h row stride in fp16 elements
#define LAYERS  5

typedef _Float16 half8 __attribute__((ext_vector_type(8)));
typedef __attribute__((ext_vector_type(4))) float floatx4;
typedef float v2f __attribute__((ext_vector_type(2)));

__device__ __forceinline__ v2f h2f(__half2 h) {
  float2 f = __half22float2(h);
  v2f r; r.x = f.x; r.y = f.y; return r;
}

// ---------------- fused prep: zero deg/stat, convert weights, embed ----------------
__global__ __launch_bounds__(256)
void prep_kernel(const float* __restrict__ W1, const float* __restrict__ W2,
                 const float* __restrict__ b1, const float* __restrict__ b2,
                 const int* __restrict__ x, const float* __restrict__ emb1,
                 const float* __restrict__ emb2,
                 __half* __restrict__ w1t, __half* __restrict__ w2t,
                 float* __restrict__ b1p, float* __restrict__ b2p,
                 __half* __restrict__ h, int* __restrict__ deg,
                 float* __restrict__ stat) {
  const int Z0 = N_NODES;                       // deg zero
  const int Z1 = Z0 + LAYERS * 2 * EMB;         // stat zero
  const int R0 = Z1 + LAYERS * NP1 * K1;        // w1t
  const int R1 = R0 + LAYERS * NP2 * NP1;       // w2t
  const int R2 = R1 + LAYERS * NP1;             // b1p
  const int R3 = R2 + LAYERS * NP2;             // b2p
  const int R4 = R3 + N_NODES * HSH;            // embed
  for (int i = blockIdx.x * 256 + threadIdx.x; i < R4; i += gridDim.x * 256) {
    if (i < Z0) {
      deg[i] = 0;
    } else if (i < Z1) {
      stat[i - Z0] = 0.f;
    } else if (i < R0) {
      int idx = i - Z1;
      int l = idx / (NP1 * K1);
      int rem = idx % (NP1 * K1);
      int n = rem / K1, k = rem % K1;
      float v = (n < 2 * EMB && k < EMB)
                    ? W1[(size_t)l * EMB * 2 * EMB + (size_t)k * 2 * EMB + n] : 0.f;
      w1t[idx] = __float2half(v);
    } else if (i < R1) {
      int idx = i - R0;
      int l = idx / (NP2 * NP1);
      int rem = idx % (NP2 * NP1);
      int n = rem / NP1, k = rem % NP1;
      float v = (n < EMB && k < 2 * EMB)
                    ? W2[(size_t)l * 2 * EMB * EMB + (size_t)k * EMB + n] : 0.f;
      w2t[idx] = __float2half(v);
    } else if (i < R2) {
      int idx = i - R1;
      int l = idx / NP1, j = idx % NP1;
      b1p[idx] = (j < 2 * EMB) ? b1[l * 2 * EMB + j] : 0.f;
    } else if (i < R3) {
      int idx = i - R2;
      int l = idx / NP2, j = idx % NP2;
      b2p[idx] = (j < EMB) ? b2[l * EMB + j] : 0.f;
    } else {
      int j = i - R3;
      int node = j / HSH, c = j - node * HSH;
      if (c < EMB) {
        int t0 = x[node * 2], t1 = x[node * 2 + 1];
        h[(size_t)node * HSH + c] = __float2half(emb1[t0 * EMB + c] + emb2[t1 * EMB + c]);
      }
    }
  }
}

// ---------------- CSR build ----------------
__global__ void count_kernel(const int* __restrict__ ei, int* __restrict__ deg) {
  int e = blockIdx.x * 256 + threadIdx.x;
  if (e < N_EDGES) atomicAdd(&deg[ei[N_EDGES + e]], 1);
}

#define SCH 30   // 1024 * 30 = 30720 >= N_NODES
__global__ __launch_bounds__(1024)
void scan_kernel(const int* __restrict__ deg, int* __restrict__ row_ptr,
                 int* __restrict__ curs) {
  int tid = threadIdx.x;
  int base = tid * SCH;
  int loc[SCH];
  int s = 0;
#pragma unroll
  for (int j = 0; j < SCH; ++j) {
    int i = base + j;
    int v = (i < N_NODES) ? deg[i] : 0;
    loc[j] = s;          // exclusive prefix within chunk
    s += v;
  }
  int lane = tid & 63, wv = tid >> 6;
  int x = s;
#pragma unroll
  for (int o = 1; o < 64; o <<= 1) {
    int y = __shfl_up(x, o, 64);
    if (lane >= o) x += y;
  }
  __shared__ int wsum[16], woff[16];
  if (lane == 63) wsum[wv] = x;
  __syncthreads();
  if (tid == 0) {
    int acc = 0;
    for (int w = 0; w < 16; ++w) { woff[w] = acc; acc += wsum[w]; }
    row_ptr[N_NODES] = acc;
  }
  __syncthreads();
  int excl = woff[wv] + x - s;    // exclusive prefix of this thread's chunk
#pragma unroll
  for (int j = 0; j < SCH; ++j) {
    int i = base + j;
    if (i < N_NODES) { int val = excl + loc[j]; row_ptr[i] = val; curs[i] = val; }
  }
}

__global__ void fill_kernel(const int* __restrict__ ei, const int* __restrict__ ea,
                            int* __restrict__ cursor, int* __restrict__ ebuf) {
  int e = blockIdx.x * 256 + threadIdx.x;
  if (e >= N_EDGES) return;
  int d = ei[N_EDGES + e];
  int pos = atomicAdd(&cursor[d], 1);
  ebuf[pos] = ei[e] * 32 + (ea[2 * e] * 3 + ea[2 * e + 1]);  // src*32 + combo
}

// ---------------- aggregation: fp16 gather-sum, 8x edge unroll ----------------
// UNCHANGED from R4 (isolates the GEMM rewrite).
__global__ __launch_bounds__(256)
void aggregate_kernel(const __half* __restrict__ h,
                      const int* __restrict__ row_ptr,
                      const int* __restrict__ ebuf,
                      const float* __restrict__ e1,   // [6,300] this layer
                      const float* __restrict__ e2,   // [3,300] this layer
                      __half* __restrict__ agg) {
  __shared__ __half2 combo[18][150];   // 10.8 KB
  int tid = threadIdx.x;
  for (int idx = tid; idx < 18 * 150; idx += 256) {
    int t = idx / 150, p = idx % 150;
    int a0 = t / 3, a1 = t % 3;
    combo[t][p] = __floats2half2_rn(e1[a0 * EMB + 2 * p]     + e2[a1 * EMB + 2 * p],
                                    e1[a0 * EMB + 2 * p + 1] + e2[a1 * EMB + 2 * p + 1]);
  }
  __syncthreads();
  int wave = tid >> 6, lane = tid & 63;
  int node = blockIdx.x * 4 + wave;
  v2f A0 = {0.f, 0.f}, A1 = {0.f, 0.f}, A2 = {0.f, 0.f};
  v2f B0 = {0.f, 0.f}, B1 = {0.f, 0.f}, B2 = {0.f, 0.f};
  int p2 = lane + 128;
  bool has2 = (p2 < 150);
  if (node < N_NODES) {
    int ebeg = row_ptr[node], eend = row_ptr[node + 1];
    int e = ebeg;
    // ---- 8-edge unrolled main loop: issue ALL 24 gathers, then accumulate ----
    for (; e + 8 <= eend; e += 8) {
      int v[8];
#pragma unroll
      for (int j = 0; j < 8; ++j) v[j] = ebuf[e + j];
      const __half2* hp[8];
#pragma unroll
      for (int j = 0; j < 8; ++j) hp[j] = (const __half2*)(h + (size_t)(v[j] >> 5) * HSH);
      __half2 x0[8], x1[8], x2[8];
#pragma unroll
      for (int j = 0; j < 8; ++j) { x0[j] = hp[j][lane]; x1[j] = hp[j][lane + 64]; }
      if (has2) {
#pragma unroll
        for (int j = 0; j < 8; ++j) x2[j] = hp[j][p2];
      }
#pragma unroll
      for (int j = 0; j < 8; ++j) {
        int tc = v[j] & 31;
        if (j & 1) {
          B0 += h2f(x0[j]) + h2f(combo[tc][lane]);
          B1 += h2f(x1[j]) + h2f(combo[tc][lane + 64]);
          if (has2) B2 += h2f(x2[j]) + h2f(combo[tc][p2]);
        } else {
          A0 += h2f(x0[j]) + h2f(combo[tc][lane]);
          A1 += h2f(x1[j]) + h2f(combo[tc][lane + 64]);
          if (has2) A2 += h2f(x2[j]) + h2f(combo[tc][p2]);
        }
      }
    }
    // ---- 2-edge pairs ----
    for (; e + 2 <= eend; e += 2) {
      int v0 = ebuf[e], v1 = ebuf[e + 1];
      const __half2* hp0 = (const __half2*)(h + (size_t)(v0 >> 5) * HSH);
      const __half2* hp1 = (const __half2*)(h + (size_t)(v1 >> 5) * HSH);
      int t0 = v0 & 31, t1 = v1 & 31;
      __half2 x00 = hp0[lane], x01 = hp0[lane + 64];
      __half2 x10 = hp1[lane], x11 = hp1[lane + 64];
      A0 += h2f(x00) + h2f(combo[t0][lane]);
      A1 += h2f(x01) + h2f(combo[t0][lane + 64]);
      B0 += h2f(x10) + h2f(combo[t1][lane]);
      B1 += h2f(x11) + h2f(combo[t1][lane + 64]);
      if (has2) {
        A2 += h2f(hp0[p2]) + h2f(combo[t0][p2]);
        B2 += h2f(hp1[p2]) + h2f(combo[t1][p2]);
      }
    }
    // ---- tail edge (if odd count) + self loop ----
    for (; e <= eend; ++e) {
      int s, t;
      if (e < eend) { int v = ebuf[e]; s = v >> 5; t = v & 31; }
      else          { s = node;        t = 4 * 3 + 0; }
      const __half2* hp = (const __half2*)(h + (size_t)s * HSH);
      A0 += h2f(hp[lane])      + h2f(combo[t][lane]);
      A1 += h2f(hp[lane + 64]) + h2f(combo[t][lane + 64]);
      if (has2) A2 += h2f(hp[p2]) + h2f(combo[t][p2]);
    }
  }
  A0 += B0; A1 += B1; A2 += B2;
  __half2* op = (__half2*)(agg + (size_t)node * K1);
  op[lane]      = __floats2half2_rn(A0.x, A0.y);
  op[lane + 64] = __floats2half2_rn(A1.x, A1.y);
  if (p2 < 160) op[p2] = has2 ? __floats2half2_rn(A2.x, A2.y)
                              : __floats2half2_rn(0.f, 0.f);   // zero K-pad cols
}

// ---------------- fp16 MFMA GEMM: C = act(A @ B^T + bias) ----------------
// v5: BARRIER-FREE. R4 counters (MfmaUtil 9%, VALUBusy 8%, Occ 22%) proved
// the block was stall-bound: 4 waves lockstepped by 2 s_barriers/K-step with
// only ~2.75 blocks/CU -> every unhidden load latency convoys the whole CU.
// MFMA fragments are per-lane-private, so nothing here needs LDS or cross-
// wave sync: each wave owns a 64x64 output tile and loads its 4 A-frags +
// 4 B-frags direct global->VGPR (per-lane dwordx4; B-frag path correctness-
// proven in R4, A uses the identical mapping), ping-pong prefetched one
// K-step ahead with STATIC buffer names (rule #20). No barriers -> waves
// slip freely; pure register deps -> compiler's own counted s_waitcnt
// scheduling (guide G7) with nothing to drain.
#define MFMA16(AF, BF)                                                              \
  _Pragma("unroll")                                                                 \
  for (int mi = 0; mi < 4; ++mi)                                                    \
    _Pragma("unroll")                                                               \
    for (int ni = 0; ni < 4; ++ni)                                                  \
      acc[mi][ni] = __builtin_amdgcn_mfma_f32_16x16x32_f16(AF[mi], BF[ni], acc[mi][ni], 0, 0, 0);

template<int RELU, int STATS>
__global__ __launch_bounds__(256, 3)
void gemm_kernel(const __half* __restrict__ A, int lda,
                 const __half* __restrict__ Bt, int ldb,
                 const float* __restrict__ bias,
                 __half* __restrict__ C, int ldc, int K,
                 float* __restrict__ stats) {
  __shared__ float cs[128], cq[128];
  int tid = threadIdx.x;
  int wave = tid >> 6, lane = tid & 63;
  int wm = wave >> 1, wn = wave & 1;
  int bcol0 = blockIdx.x * 128;
  int row0 = blockIdx.y * 128 + wm * 64;
  int col0 = bcol0 + wn * 64;
  int lr = lane & 15, lk = (lane >> 4) * 8;   // frag row-in-16 / k-chunk

  if (STATS && tid < 128) { cs[tid] = 0.f; cq[tid] = 0.f; }
  if (STATS) __syncthreads();   // init visible before any wave's epilogue atomics

  const __half* ga0 = A + (size_t)(row0 +  0 + lr) * lda + lk;
  const __half* ga1 = A + (size_t)(row0 + 16 + lr) * lda + lk;
  const __half* ga2 = A + (size_t)(row0 + 32 + lr) * lda + lk;
  const __half* ga3 = A + (size_t)(row0 + 48 + lr) * lda + lk;
  const __half* gb0 = Bt + (size_t)(col0 +  0 + lr) * ldb + lk;
  const __half* gb1 = Bt + (size_t)(col0 + 16 + lr) * ldb + lk;
  const __half* gb2 = Bt + (size_t)(col0 + 32 + lr) * ldb + lk;
  const __half* gb3 = Bt + (size_t)(col0 + 48 + lr) * ldb + lk;

  floatx4 zero4 = {0.f, 0.f, 0.f, 0.f};
  floatx4 acc[4][4];
#pragma unroll
  for (int i = 0; i < 4; ++i)
#pragma unroll
    for (int j = 0; j < 4; ++j) acc[i][j] = zero4;

  half8 afA[4], bfA[4], afB[4], bfB[4];
  // prologue: K-step 0 into A-buffers
  afA[0] = *(const half8*)(ga0); afA[1] = *(const half8*)(ga1);
  afA[2] = *(const half8*)(ga2); afA[3] = *(const half8*)(ga3);
  bfA[0] = *(const half8*)(gb0); bfA[1] = *(const half8*)(gb1);
  bfA[2] = *(const half8*)(gb2); bfA[3] = *(const half8*)(gb3);

  int nT = K >> 5;   // 10 (gemm1) or 20 (gemm2): always even
  for (int t = 0; t + 2 <= nT; t += 2) {
    int kc1 = (t + 1) << 5;
    afB[0] = *(const half8*)(ga0 + kc1); afB[1] = *(const half8*)(ga1 + kc1);
    afB[2] = *(const half8*)(ga2 + kc1); afB[3] = *(const half8*)(ga3 + kc1);
    bfB[0] = *(const half8*)(gb0 + kc1); bfB[1] = *(const half8*)(gb1 + kc1);
    bfB[2] = *(const half8*)(gb2 + kc1); bfB[3] = *(const half8*)(gb3 + kc1);
    MFMA16(afA, bfA);
    if (t + 2 < nT) {
      int kc2 = (t + 2) << 5;
      afA[0] = *(const half8*)(ga0 + kc2); afA[1] = *(const half8*)(ga1 + kc2);
      afA[2] = *(const half8*)(ga2 + kc2); afA[3] = *(const half8*)(ga3 + kc2);
      bfA[0] = *(const half8*)(gb0 + kc2); bfA[1] = *(const half8*)(gb1 + kc2);
      bfA[2] = *(const half8*)(gb2 + kc2); bfA[3] = *(const half8*)(gb3 + kc2);
    }
    MFMA16(afB, bfB);
  }

  // epilogue: C/D layout col=lane&15, row=quad*4+reg
  float ls[4] = {0.f, 0.f, 0.f, 0.f}, lq[4] = {0.f, 0.f, 0.f, 0.f};
#pragma unroll
  for (int mi = 0; mi < 4; ++mi) {
#pragma unroll
    for (int ni = 0; ni < 4; ++ni) {
      int col = col0 + ni * 16 + lr;
      float bv = bias[col];
#pragma unroll
      for (int r = 0; r < 4; ++r) {
        int row = row0 + mi * 16 + (lane >> 4) * 4 + r;
        float v = acc[mi][ni][r] + bv;
        if (RELU) v = fmaxf(v, 0.f);
        C[(size_t)row * ldc + col] = __float2half(v);
        if (STATS && row < N_NODES) { ls[ni] += v; lq[ni] += v * v; }
      }
    }
  }
  if (STATS) {
#pragma unroll
    for (int ni = 0; ni < 4; ++ni) {
      int ci = (wn << 6) + ni * 16 + lr;
      atomicAdd(&cs[ci], ls[ni]);
      atomicAdd(&cq[ci], lq[ni]);
    }
    __syncthreads();
    int col = bcol0 + tid;
    if (tid < 128 && col < EMB) {
      atomicAdd(&stats[col], cs[tid]);
      atomicAdd(&stats[EMB + col], cq[tid]);
    }
  }
}

// ---------------- batchnorm apply (+relu), grid-stride half2 ----------------
__global__ __launch_bounds__(256)
void bn_kernel(const __half* __restrict__ h2, const float* __restrict__ stats,
               const float* __restrict__ gamma, const float* __restrict__ beta,
               __half* __restrict__ hout, float* __restrict__ fout, int relu) {
  const float invN = 1.0f / (float)N_NODES;
  const int total = N_NODES * 150;
  for (int i = blockIdx.x * 256 + threadIdx.x; i < total; i += gridDim.x * 256) {
    int node = i / 150;
    int c = (i - node * 150) * 2;
    float m0 = stats[c] * invN,      m1 = stats[c + 1] * invN;
    float v0 = stats[EMB + c] * invN - m0 * m0;
    float v1 = stats[EMB + c + 1] * invN - m1 * m1;
    float s0 = gamma[c] * rsqrtf(v0 + 1e-5f);
    float s1 = gamma[c + 1] * rsqrtf(v1 + 1e-5f);
    float t0 = beta[c] - m0 * s0, t1 = beta[c + 1] - m1 * s1;
    float2 u = __half22float2(*(const __half2*)&h2[(size_t)node * NP2 + c]);
    float r0 = u.x * s0 + t0, r1 = u.y * s1 + t1;
    if (relu) { r0 = fmaxf(r0, 0.f); r1 = fmaxf(r1, 0.f); }
    if (hout) {
      *(__half2*)&hout[(size_t)node * HSH + c] = __floats2half2_rn(r0, r1);
    } else {
      fout[(size_t)node * EMB + c]     = r0;
      fout[(size_t)node * EMB + c + 1] = r1;
    }
  }
}

extern "C" void kernel_launch(void* const* d_in, const int* in_sizes, int n_in,
                              void* d_out, int out_size, void* d_ws, size_t ws_size,
                              hipStream_t stream) {
  const int*   x      = (const int*)d_in[0];
  const int*   ei     = (const int*)d_in[1];
  const int*   ea     = (const int*)d_in[2];
  const float* x_emb1 = (const float*)d_in[3];
  const float* x_emb2 = (const float*)d_in[4];
  const float* edge1  = (const float*)d_in[5];
  const float* edge2  = (const float*)d_in[6];
  const float* W1     = (const float*)d_in[7];
  const float* b1     = (const float*)d_in[8];
  const float* W2     = (const float*)d_in[9];
  const float* b2     = (const float*)d_in[10];
  const float* gamma  = (const float*)d_in[11];
  const float* beta   = (const float*)d_in[12];
  float* out = (float*)d_out;

  char* ws = (char*)d_ws;
  size_t off = 0;
  auto nxt = [&](size_t bytes) {
    void* p = ws + off;
    off += (bytes + 255) & ~(size_t)255;
    return p;
  };
  // Region R: tbuf (fp16 [NPAD][NP1], live gemm1->gemm2) aliases hbuf
  // (fp16 [N_NODES][HSH], read only by aggregate, rewritten by bn).
  size_t tbuf_bytes = (size_t)NPAD * NP1 * 2;        // 38.5 MB
  size_t hbuf_bytes = (size_t)N_NODES * HSH * 2;     // 18.2 MB
  char* R = (char*)nxt(tbuf_bytes > hbuf_bytes ? tbuf_bytes : hbuf_bytes);
  __half* hbuf = (__half*)R;
  __half* tbuf = (__half*)R;
  // Region S: aggb (fp16 [NPAD][K1], live aggregate->gemm1) aliases h2
  // (fp16 [NPAD][NP2], live gemm2->bn).
  size_t agg_bytes = (size_t)NPAD * K1 * 2;          // 19.3 MB
  size_t h2_bytes  = (size_t)NPAD * NP2 * 2;         // 23.1 MB
  char* S = (char*)nxt(agg_bytes > h2_bytes ? agg_bytes : h2_bytes);
  __half* aggb = (__half*)S;
  __half* h2   = (__half*)S;
  __half* w1t  = (__half*)nxt((size_t)LAYERS * NP1 * K1 * 2);
  __half* w2t  = (__half*)nxt((size_t)LAYERS * NP2 * NP1 * 2);
  float*  b1p  = (float*)nxt((size_t)LAYERS * NP1 * 4);
  float*  b2p  = (float*)nxt((size_t)LAYERS * NP2 * 4);
  float*  stat = (float*)nxt((size_t)LAYERS * 2 * EMB * 4);
  int*    deg  = (int*)nxt((size_t)N_NODES * 4);
  int*    rptr = (int*)nxt((size_t)(N_NODES + 1) * 4);
  int*    curs = (int*)nxt((size_t)N_NODES * 4);
  int*    ebuf = (int*)nxt((size_t)N_EDGES * 4);
  // total ~68 MB

  prep_kernel<<<2048, 256, 0, stream>>>(W1, W2, b1, b2, x, x_emb1, x_emb2,
                                        w1t, w2t, b1p, b2p, hbuf, deg, stat);

  count_kernel<<<(N_EDGES + 255) / 256, 256, 0, stream>>>(ei, deg);
  scan_kernel<<<1, 1024, 0, stream>>>(deg, rptr, curs);
  fill_kernel<<<(N_EDGES + 255) / 256, 256, 0, stream>>>(ei, ea, curs, ebuf);

  for (int l = 0; l < LAYERS; ++l) {
    aggregate_kernel<<<NPAD / 4, 256, 0, stream>>>(
        hbuf, rptr, ebuf, edge1 + (size_t)l * 6 * EMB, edge2 + (size_t)l * 3 * EMB, aggb);
    gemm_kernel<1, 0><<<dim3(NP1 / 128, NPAD / 128), 256, 0, stream>>>(
        aggb, K1, w1t + (size_t)l * NP1 * K1, K1, b1p + l * NP1, tbuf, NP1, K1, nullptr);
    gemm_kernel<0, 1><<<dim3(NP2 / 128, NPAD / 128), 256, 0, stream>>>(
        tbuf, NP1, w2t + (size_t)l * NP2 * NP1, NP1, b2p + l * NP2, h2, NP2, NP1,
        stat + l * 2 * EMB);
    bn_kernel<<<1024, 256, 0, stream>>>(
        h2, stat + l * 2 * EMB, gamma + l * EMB, beta + l * EMB,
        (l < LAYERS - 1) ? hbuf : (__half*)nullptr,
        (l < LAYERS - 1) ? (float*)nullptr : out,
        (l < LAYERS - 1) ? 1 : 0);
  }
}